// Round 7
// baseline (851.662 us; speedup 1.0000x reference)
//
#include <hip/hip_runtime.h>
#include <stdint.h>

#define V_ITEMS 100000
#define EDIM    128
#define BATCH   4096
#define HLEN    50
#define TOPK    21

#define MT      32            // batches per block in K2
#define VSPLIT  8             // item ranges; range = blockIdx&7 -> XCD-locked
#define TOTCH   (V_ITEMS / 16)         // 6250 16-item chunks total
#define CAP2    128           // per-batch candidate capacity (LDS)
#define ELANE   (CAP2 / 64)   // candidate elems per lane in compaction
#define NKEEP   32            // superset kept per (batch, range)
#define NCAND   (NKEEP * VSPLIT)       // 256 candidates per batch into K3
// TRIG=48: thr is STATIC between compactions -> insert rate is 32/window.
// Mean cnt at each doubling event = 64; TRIG must sit below that or events
// skip and cnt hits CAP2 (TRIG=96 did that in R4/R5 -> mass candidate drops).
#define TRIG    48

typedef __attribute__((ext_vector_type(8))) short          bf16x8;
typedef __attribute__((ext_vector_type(4))) float          f32x4;
typedef __attribute__((ext_vector_type(8))) unsigned short u16x8;

__device__ inline unsigned short f2bf(float x) {           // RNE fp32->bf16
    unsigned u = __float_as_uint(x);
    return (unsigned short)((u + 0x7FFFu + ((u >> 16) & 1u)) >> 16);
}

// ---------------- K0: emb fp32 -> bf16 table in ws --------------------------
__global__ __launch_bounds__(256) void conv_bf16(
        const float* __restrict__ s, unsigned short* __restrict__ d) {
    size_t i = (size_t)blockIdx.x * 256 + threadIdx.x;     // 8 floats/thread
    const float4* sp = (const float4*)s + i * 2;
    float4 a = sp[0], b = sp[1];
    u16x8 o;
    o[0] = f2bf(a.x); o[1] = f2bf(a.y); o[2] = f2bf(a.z); o[3] = f2bf(a.w);
    o[4] = f2bf(b.x); o[5] = f2bf(b.y); o[6] = f2bf(b.z); o[7] = f2bf(b.w);
    *((u16x8*)d + i) = o;
}

// ---------------- K1: masked mean-pool queries -> bf16 ----------------------
__global__ __launch_bounds__(EDIM) void query_bf16(
        const int* __restrict__ seq, const int* __restrict__ len,
        const float* __restrict__ emb, unsigned short* __restrict__ qbf) {
    int b = blockIdx.x, d = threadIdx.x;
    int n = len[b];
    float s = 0.f;
    for (int l = 0; l < n; l++)
        s += emb[(size_t)seq[b * HLEN + l] * EDIM + d];
    qbf[b * EDIM + d] = f2bf(s / (float)(n > 0 ? n : 1));
}

// ---- exact top-32 of a batch's candidate buffer ----------------------------
// 64-bit TOTAL-ORDER key (score, then low idx): R6 tripwire root cause was
// score-only keys — exact fp32 ties at the rank-32 boundary made the kept set
// depend on atomicAdd arrival order (~13 expected boundary ties/run).
__device__ inline void compact_batch(float* cv, int* ci, int* cnt, float* thr,
                                     int b, int lane) {
    int n = min(cnt[b], CAP2);
    float val[ELANE]; int idx[ELANE]; uint64_t key[ELANE];
    #pragma unroll
    for (int e = 0; e < ELANE; e++) {
        int i = lane + e * 64;
        if (i < n) {
            float v = cv[b * CAP2 + i];
            int  id = ci[b * CAP2 + i];
            unsigned u = __float_as_uint(v);
            u = (u & 0x80000000u) ? ~u : (u | 0x80000000u);
            key[e] = ((uint64_t)u << 32) | (uint64_t)(0xFFFFFFFFu - (unsigned)id);
            val[e] = v; idx[e] = id;
        } else { key[e] = 0ull; val[e] = 0.f; idx[e] = 0; }
    }
    uint64_t cur = 0ull;               // max T with count(key >= T) >= 32
    #pragma unroll 1
    for (int bit = 63; bit >= 0; bit--) {
        uint64_t mid = cur | (1ull << bit);
        int c = 0;
        #pragma unroll
        for (int e = 0; e < ELANE; e++)
            c += __popcll(__ballot(key[e] >= mid));
        if (c >= 32) cur = mid;
    }
    int base = 0;                      // exactly 32 kept (keys unique)
    #pragma unroll
    for (int e = 0; e < ELANE; e++) {
        bool keep = key[e] >= cur;
        unsigned long long m = __ballot(keep);
        int p = base + (int)__popcll(m & ((1ull << lane) - 1ull));
        if (keep) { cv[b * CAP2 + p] = val[e]; ci[b * CAP2 + p] = idx[e]; }
        base += (int)__popcll(m);
    }
    if (lane == 0) {
        cnt[b] = NKEEP;
        unsigned sk = (unsigned)(cur >> 32);   // 32nd item's score bits
        thr[b] = (sk & 0x80000000u) ? __uint_as_float(sk ^ 0x80000000u)
                                    : __uint_as_float(~sk);
    }
}

// ---------------- K2: bf16-MFMA scoring + fused per-range top-32 ------------
// grid = 128 batch-groups x 8 ranges. range = blockIdx&7 so (round-robin
// block->XCD) each XCD sweeps ONE 3.2 MB bf16 range -> L2-resident.
// B-chunk register double-buffer breaks R3's serialized load->mfma->insert.
__global__ __launch_bounds__(512) void score_topk(
        const unsigned short* __restrict__ qbf,
        const unsigned short* __restrict__ ebf,
        int* __restrict__ candI) {
    __shared__ float cv[MT * CAP2];    // 16 KB
    __shared__ int   ci[MT * CAP2];    // 16 KB
    __shared__ int   cnt[MT];
    __shared__ float thr[MT];

    const int tid  = threadIdx.x;
    const int lane = tid & 63;
    const int w    = tid >> 6;                       // wave 0..7
    const int vr   = blockIdx.x & 7;                 // item range (XCD-locked)
    const int mg   = blockIdx.x >> 3;                // batch group
    const int b0   = mg * MT;
    const int n15  = lane & 15, quad = lane >> 4;

    const int cstart  = (vr * TOTCH) >> 3;
    const int cend    = ((vr + 1) * TOTCH) >> 3;
    const int niter   = (cend - cstart + 7) >> 3;

    if (tid < MT) { cnt[tid] = 0; thr[tid] = -INFINITY; }
    __syncthreads();

    // resident A-fragments: 2 msubs x 4 K-steps (32 VGPRs)
    bf16x8 afr[2][4];
    #pragma unroll
    for (int ms = 0; ms < 2; ms++)
        #pragma unroll
        for (int t = 0; t < 4; t++)
            afr[ms][t] = *(const bf16x8*)(qbf + (b0 + ms * 16 + n15) * EDIM
                                          + t * 32 + quad * 8);
    float thrR[8];
    #pragma unroll
    for (int i = 0; i < 8; i++) thrR[i] = -INFINITY;

    // prime B double-buffer with this wave's first chunk
    bf16x8 bc[4];
    {
        int cc = cstart + w; if (cc >= cend) cc = cend - 1;
        const unsigned short* bp = ebf + (cc * 16 + n15) * EDIM + quad * 8;
        #pragma unroll
        for (int t = 0; t < 4; t++) bc[t] = *(const bf16x8*)(bp + t * 32);
    }

    int nextEvt = 1;
    for (int iter = 0; iter < niter; iter++) {
        // ---- prefetch next iteration's chunk (dup-load on last iter, harmless)
        bf16x8 bn[4];
        {
            int cn = cstart + (iter + 1) * 8 + w; if (cn >= cend) cn = cend - 1;
            const unsigned short* bp = ebf + (cn * 16 + n15) * EDIM + quad * 8;
            #pragma unroll
            for (int t = 0; t < 4; t++) bn[t] = *(const bf16x8*)(bp + t * 32);
        }
        const int chunk = cstart + iter * 8 + w;
        const bool act  = chunk < cend;

        f32x4 acc0 = {0.f, 0.f, 0.f, 0.f}, acc1 = {0.f, 0.f, 0.f, 0.f};
        #pragma unroll
        for (int t = 0; t < 4; t++) {
            acc0 = __builtin_amdgcn_mfma_f32_16x16x32_bf16(afr[0][t], bc[t], acc0, 0, 0, 0);
            acc1 = __builtin_amdgcn_mfma_f32_16x16x32_bf16(afr[1][t], bc[t], acc1, 0, 0, 0);
        }
        // C/D: item col = lane&15, batch row = quad*4 + reg  [m89/m91]
        if (act) {
            int item = chunk * 16 + n15;
            #pragma unroll
            for (int ms = 0; ms < 2; ms++)
                #pragma unroll
                for (int r = 0; r < 4; r++) {
                    float s = ms ? acc1[r] : acc0[r];
                    if (s > thrR[ms * 4 + r]) {
                        int row = ms * 16 + (quad << 2) + r;
                        int pz = atomicAdd(&cnt[row], 1);
                        if (pz < CAP2) { cv[row * CAP2 + pz] = s; ci[row * CAP2 + pz] = item; }
                    }
                }
        }
        // static compaction schedule: iters 1,2,4,...; plus final iter.
        if (iter + 1 == nextEvt || iter + 1 == niter) {
            if (iter + 1 == nextEvt) nextEvt <<= 1;
            bool fin = (iter + 1 == niter);
            __syncthreads();
            #pragma unroll 1
            for (int j = 0; j < 4; j++) {
                int b = (w << 2) + j;
                if (fin || cnt[b] > TRIG) compact_batch(cv, ci, cnt, thr, b, lane);
            }
            __syncthreads();
            #pragma unroll
            for (int ms = 0; ms < 2; ms++)
                #pragma unroll
                for (int r = 0; r < 4; r++)
                    thrR[ms * 4 + r] = thr[ms * 16 + (quad << 2) + r];
        }
        #pragma unroll
        for (int t = 0; t < 4; t++) bc[t] = bn[t];
    }
    // final compact guaranteed cnt==32/batch; emit candidate indices
    for (int j = 0; j < 4; j++) {
        int b = (w << 2) + j;
        if (lane < NKEEP)
            candI[(b0 + b) * NCAND + vr * NKEEP + lane] = ci[b * CAP2 + lane];
    }
}

// ---------------- K3: fp64 rescore of all 256 candidates, exact top-21 ------
__global__ __launch_bounds__(NCAND) void rescore(
        const int* __restrict__ seq, const int* __restrict__ len,
        const float* __restrict__ emb, const int* __restrict__ candI,
        float* __restrict__ out) {
    __shared__ double qd[EDIM];
    __shared__ double sv[NCAND];
    __shared__ int    si[NCAND];
    int b = blockIdx.x, t = threadIdx.x;

    if (t < EDIM) {
        int n = len[b];
        double s = 0.0;
        for (int l = 0; l < n; l++)
            s += (double)emb[(size_t)seq[b * HLEN + l] * EDIM + t];
        qd[t] = s / (double)(n > 0 ? n : 1);
    }
    __syncthreads();

    int idx = candI[(size_t)b * NCAND + t];
    const float4* ev = (const float4*)(emb + (size_t)idx * EDIM);
    double acc = 0.0;
    #pragma unroll 8
    for (int j = 0; j < EDIM / 4; j++) {
        float4 e = ev[j];
        int d = j * 4;
        acc += qd[d] * (double)e.x + qd[d + 1] * (double)e.y
             + qd[d + 2] * (double)e.z + qd[d + 3] * (double)e.w;
    }
    sv[t] = acc; si[t] = idx;
    __syncthreads();

    double v = sv[t]; int id = si[t];                // exact fp64 rank among 256
    int rank = 0;
    for (int j = 0; j < NCAND; j++) {
        double vj = sv[j]; int ij = si[j];
        rank += (vj > v || (vj == v && ij < id)) ? 1 : 0;
    }
    if (rank < TOPK) {
        out[(size_t)b * TOPK + rank] = (float)v;
        out[(size_t)BATCH * TOPK + (size_t)b * TOPK + rank] = (float)id;
    }
}

extern "C" void kernel_launch(void* const* d_in, const int* in_sizes, int n_in,
                              void* d_out, int out_size, void* d_ws, size_t ws_size,
                              hipStream_t stream) {
    const int*   seq = (const int*)d_in[0];
    const int*   len = (const int*)d_in[1];
    const float* emb = (const float*)d_in[2];
    float* out = (float*)d_out;

    // ws: qbf [1 MB] | ebf [25.6 MB] | candI [4 MB]  = 29.4 MiB total
    unsigned short* qbf  = (unsigned short*)d_ws;
    unsigned short* ebf  = qbf + (size_t)BATCH * EDIM;
    int*            cI   = (int*)(ebf + (size_t)V_ITEMS * EDIM);

    conv_bf16 <<<(V_ITEMS * EDIM) / (256 * 8), 256, 0, stream>>>(emb, ebf);
    query_bf16<<<BATCH, EDIM, 0, stream>>>(seq, len, emb, qbf);
    score_topk<<<(BATCH / MT) * VSPLIT, 512, 0, stream>>>(qbf, ebf, cI);
    rescore   <<<BATCH, NCAND, 0, stream>>>(seq, len, emb, cI, out);
}

// Round 8
// 744.378 us; speedup vs baseline: 1.1441x; 1.1441x over previous
//
#include <hip/hip_runtime.h>
#include <stdint.h>

#define V_ITEMS 100000
#define EDIM    128
#define BATCH   4096
#define HLEN    50
#define TOPK    21

#define MT      32            // batches per block in K2
#define VSPLIT  8             // item ranges; range = blockIdx&7 -> XCD-locked
#define TOTCH   (V_ITEMS / 16)         // 6250 16-item chunks total
#define CAP2    128           // per-batch candidate capacity (LDS)
#define ELANE   (CAP2 / 64)   // candidate elems per lane in compaction
#define NKEEP   32            // superset kept per (batch, range)
#define NCAND   (NKEEP * VSPLIT)       // 256 candidates per batch into K3
// TRIG=48: thr is STATIC between compactions -> insert rate is 32/window.
// Mean cnt at each doubling event = 64; TRIG must sit below that or events
// skip and cnt hits CAP2 (TRIG=96 did that in R4/R5 -> mass candidate drops).
#define TRIG    48

typedef __attribute__((ext_vector_type(8))) short          bf16x8;
typedef __attribute__((ext_vector_type(4))) float          f32x4;
typedef __attribute__((ext_vector_type(8))) unsigned short u16x8;

__device__ inline unsigned short f2bf(float x) {           // RNE fp32->bf16
    unsigned u = __float_as_uint(x);
    return (unsigned short)((u + 0x7FFFu + ((u >> 16) & 1u)) >> 16);
}

// ---------------- K0: emb fp32 -> bf16 in MFMA-B-FRAGMENT ORDER -------------
// Layout: chunk c (16 items), k-step t, lane l: flat = ((c*4 + t)*64 + l)*8+s
// holding item v=c*16+(l&15), dim d=t*32+(l>>4)*8+s. K2's wave loads become
// contiguous 1-KB blasts (R7's 16x 64-B scatter per load was the wall:
// 51M 64-B L2 transactions/dispatch at ~1/5 of L2 peak).
__global__ __launch_bounds__(256) void conv_frag(
        const float* __restrict__ s, unsigned short* __restrict__ d) {
    int g = blockIdx.x * 256 + threadIdx.x;        // one (c,t,l) per thread
    int c = g >> 8, t = (g >> 6) & 3, l = g & 63;
    int v  = c * 16 + (l & 15);
    int d0 = t * 32 + (l >> 4) * 8;
    const float4* sp = (const float4*)(s + (size_t)v * EDIM + d0);
    float4 a = sp[0], b = sp[1];
    u16x8 o;
    o[0] = f2bf(a.x); o[1] = f2bf(a.y); o[2] = f2bf(a.z); o[3] = f2bf(a.w);
    o[4] = f2bf(b.x); o[5] = f2bf(b.y); o[6] = f2bf(b.z); o[7] = f2bf(b.w);
    *((u16x8*)d + g) = o;
}

// ---------------- K1: masked mean-pool queries -> bf16 ----------------------
__global__ __launch_bounds__(EDIM) void query_bf16(
        const int* __restrict__ seq, const int* __restrict__ len,
        const float* __restrict__ emb, unsigned short* __restrict__ qbf) {
    int b = blockIdx.x, d = threadIdx.x;
    int n = len[b];
    float s = 0.f;
    for (int l = 0; l < n; l++)
        s += emb[(size_t)seq[b * HLEN + l] * EDIM + d];
    qbf[b * EDIM + d] = f2bf(s / (float)(n > 0 ? n : 1));
}

// ---- exact top-32 of a batch's candidate buffer ----------------------------
// 64-bit TOTAL-ORDER key (score, then low idx): kept set is order-independent
// (R6 tripwire: score-only keys tied at the rank-32 cut).
__device__ inline void compact_batch(float* cv, int* ci, int* cnt, float* thr,
                                     int b, int lane) {
    int n = min(cnt[b], CAP2);
    float val[ELANE]; int idx[ELANE]; uint64_t key[ELANE];
    #pragma unroll
    for (int e = 0; e < ELANE; e++) {
        int i = lane + e * 64;
        if (i < n) {
            float v = cv[b * CAP2 + i];
            int  id = ci[b * CAP2 + i];
            unsigned u = __float_as_uint(v);
            u = (u & 0x80000000u) ? ~u : (u | 0x80000000u);
            key[e] = ((uint64_t)u << 32) | (uint64_t)(0xFFFFFFFFu - (unsigned)id);
            val[e] = v; idx[e] = id;
        } else { key[e] = 0ull; val[e] = 0.f; idx[e] = 0; }
    }
    uint64_t cur = 0ull;               // max T with count(key >= T) >= 32
    #pragma unroll 1
    for (int bit = 63; bit >= 0; bit--) {
        uint64_t mid = cur | (1ull << bit);
        int c = 0;
        #pragma unroll
        for (int e = 0; e < ELANE; e++)
            c += __popcll(__ballot(key[e] >= mid));
        if (c >= 32) cur = mid;
    }
    int base = 0;                      // exactly 32 kept (keys unique)
    #pragma unroll
    for (int e = 0; e < ELANE; e++) {
        bool keep = key[e] >= cur;
        unsigned long long m = __ballot(keep);
        int p = base + (int)__popcll(m & ((1ull << lane) - 1ull));
        if (keep) { cv[b * CAP2 + p] = val[e]; ci[b * CAP2 + p] = idx[e]; }
        base += (int)__popcll(m);
    }
    if (lane == 0) {
        cnt[b] = NKEEP;
        unsigned sk = (unsigned)(cur >> 32);   // 32nd item's score bits
        thr[b] = (sk & 0x80000000u) ? __uint_as_float(sk ^ 0x80000000u)
                                    : __uint_as_float(~sk);
    }
}

// ---------------- K2: bf16-MFMA scoring + fused per-range top-32 ------------
// grid = 128 batch-groups x 8 ranges; range = blockIdx&7 -> XCD-L2-resident.
// B reads are contiguous 1-KB wave loads thanks to the fragment layout.
__global__ __launch_bounds__(512) void score_topk(
        const unsigned short* __restrict__ qbf,
        const unsigned short* __restrict__ ebf,
        int* __restrict__ candI) {
    __shared__ float cv[MT * CAP2];    // 16 KB
    __shared__ int   ci[MT * CAP2];    // 16 KB
    __shared__ int   cnt[MT];
    __shared__ float thr[MT];

    const int tid  = threadIdx.x;
    const int lane = tid & 63;
    const int w    = tid >> 6;                       // wave 0..7
    const int vr   = blockIdx.x & 7;                 // item range (XCD-locked)
    const int mg   = blockIdx.x >> 3;                // batch group
    const int b0   = mg * MT;
    const int n15  = lane & 15, quad = lane >> 4;

    const int cstart  = (vr * TOTCH) >> 3;
    const int cend    = ((vr + 1) * TOTCH) >> 3;
    const int niter   = (cend - cstart + 7) >> 3;

    if (tid < MT) { cnt[tid] = 0; thr[tid] = -INFINITY; }
    __syncthreads();

    // resident A-fragments: 2 msubs x 4 K-steps (32 VGPRs)
    bf16x8 afr[2][4];
    #pragma unroll
    for (int ms = 0; ms < 2; ms++)
        #pragma unroll
        for (int t = 0; t < 4; t++)
            afr[ms][t] = *(const bf16x8*)(qbf + (b0 + ms * 16 + n15) * EDIM
                                          + t * 32 + quad * 8);
    float thrR[8];
    #pragma unroll
    for (int i = 0; i < 8; i++) thrR[i] = -INFINITY;

    // prime B buffer with this wave's first chunk (fragment-ordered, 1 KB/load)
    bf16x8 bc[4];
    {
        int cc = cstart + w; if (cc >= cend) cc = cend - 1;
        const unsigned short* bp = ebf + (size_t)cc * 2048 + lane * 8;
        #pragma unroll
        for (int t = 0; t < 4; t++) bc[t] = *(const bf16x8*)(bp + t * 512);
    }

    int nextEvt = 1;
    for (int iter = 0; iter < niter; iter++) {
        // prefetch next chunk (compiler may collapse; loads are cheap now)
        bf16x8 bn[4];
        {
            int cn = cstart + (iter + 1) * 8 + w; if (cn >= cend) cn = cend - 1;
            const unsigned short* bp = ebf + (size_t)cn * 2048 + lane * 8;
            #pragma unroll
            for (int t = 0; t < 4; t++) bn[t] = *(const bf16x8*)(bp + t * 512);
        }
        const int chunk = cstart + iter * 8 + w;
        const bool act  = chunk < cend;

        f32x4 acc0 = {0.f, 0.f, 0.f, 0.f}, acc1 = {0.f, 0.f, 0.f, 0.f};
        #pragma unroll
        for (int t = 0; t < 4; t++) {
            acc0 = __builtin_amdgcn_mfma_f32_16x16x32_bf16(afr[0][t], bc[t], acc0, 0, 0, 0);
            acc1 = __builtin_amdgcn_mfma_f32_16x16x32_bf16(afr[1][t], bc[t], acc1, 0, 0, 0);
        }
        // C/D: item col = lane&15, batch row = quad*4 + reg  [m89/m91]
        if (act) {
            int item = chunk * 16 + n15;
            #pragma unroll
            for (int ms = 0; ms < 2; ms++)
                #pragma unroll
                for (int r = 0; r < 4; r++) {
                    float s = ms ? acc1[r] : acc0[r];
                    if (s > thrR[ms * 4 + r]) {
                        int row = ms * 16 + (quad << 2) + r;
                        int pz = atomicAdd(&cnt[row], 1);
                        if (pz < CAP2) { cv[row * CAP2 + pz] = s; ci[row * CAP2 + pz] = item; }
                    }
                }
        }
        // static compaction schedule: iters 1,2,4,...; plus final iter.
        if (iter + 1 == nextEvt || iter + 1 == niter) {
            if (iter + 1 == nextEvt) nextEvt <<= 1;
            bool fin = (iter + 1 == niter);
            __syncthreads();
            #pragma unroll 1
            for (int j = 0; j < 4; j++) {
                int b = (w << 2) + j;
                if (fin || cnt[b] > TRIG) compact_batch(cv, ci, cnt, thr, b, lane);
            }
            __syncthreads();
            #pragma unroll
            for (int ms = 0; ms < 2; ms++)
                #pragma unroll
                for (int r = 0; r < 4; r++)
                    thrR[ms * 4 + r] = thr[ms * 16 + (quad << 2) + r];
        }
        #pragma unroll
        for (int t = 0; t < 4; t++) bc[t] = bn[t];
    }
    // final compact guaranteed cnt==32/batch; emit candidate indices
    for (int j = 0; j < 4; j++) {
        int b = (w << 2) + j;
        if (lane < NKEEP)
            candI[(b0 + b) * NCAND + vr * NKEEP + lane] = ci[b * CAP2 + lane];
    }
}

// ---------------- K3: fp64 rescore of all 256 candidates, exact top-21 ------
__global__ __launch_bounds__(NCAND) void rescore(
        const int* __restrict__ seq, const int* __restrict__ len,
        const float* __restrict__ emb, const int* __restrict__ candI,
        float* __restrict__ out) {
    __shared__ double qd[EDIM];
    __shared__ double sv[NCAND];
    __shared__ int    si[NCAND];
    int b = blockIdx.x, t = threadIdx.x;

    if (t < EDIM) {
        int n = len[b];
        double s = 0.0;
        for (int l = 0; l < n; l++)
            s += (double)emb[(size_t)seq[b * HLEN + l] * EDIM + t];
        qd[t] = s / (double)(n > 0 ? n : 1);
    }
    __syncthreads();

    int idx = candI[(size_t)b * NCAND + t];
    const float4* ev = (const float4*)(emb + (size_t)idx * EDIM);
    double acc = 0.0;
    #pragma unroll 8
    for (int j = 0; j < EDIM / 4; j++) {
        float4 e = ev[j];
        int d = j * 4;
        acc += qd[d] * (double)e.x + qd[d + 1] * (double)e.y
             + qd[d + 2] * (double)e.z + qd[d + 3] * (double)e.w;
    }
    sv[t] = acc; si[t] = idx;
    __syncthreads();

    double v = sv[t]; int id = si[t];                // exact fp64 rank among 256
    int rank = 0;
    for (int j = 0; j < NCAND; j++) {
        double vj = sv[j]; int ij = si[j];
        rank += (vj > v || (vj == v && ij < id)) ? 1 : 0;
    }
    if (rank < TOPK) {
        out[(size_t)b * TOPK + rank] = (float)v;
        out[(size_t)BATCH * TOPK + (size_t)b * TOPK + rank] = (float)id;
    }
}

extern "C" void kernel_launch(void* const* d_in, const int* in_sizes, int n_in,
                              void* d_out, int out_size, void* d_ws, size_t ws_size,
                              hipStream_t stream) {
    const int*   seq = (const int*)d_in[0];
    const int*   len = (const int*)d_in[1];
    const float* emb = (const float*)d_in[2];
    float* out = (float*)d_out;

    // ws: qbf [1 MB] | ebf(frag-order) [25.6 MB] | candI [4 MB] = 29.4 MiB
    unsigned short* qbf  = (unsigned short*)d_ws;
    unsigned short* ebf  = qbf + (size_t)BATCH * EDIM;
    int*            cI   = (int*)(ebf + (size_t)V_ITEMS * EDIM);

    conv_frag <<<TOTCH, 256, 0, stream>>>(emb, ebf);          // 6250 blocks
    query_bf16<<<BATCH, EDIM, 0, stream>>>(seq, len, emb, qbf);
    score_topk<<<(BATCH / MT) * VSPLIT, 512, 0, stream>>>(qbf, ebf, cI);
    rescore   <<<BATCH, NCAND, 0, stream>>>(seq, len, emb, cI, out);
}